// Round 1
// baseline (922.631 us; speedup 1.0000x reference)
//
#include <hip/hip_runtime.h>
#include <hip/hip_bf16.h>

#define TOKENS 8192
#define IN_F   1024
#define HID_F  4096
#define OUT_F  1024
#define NEXP   8

typedef __attribute__((ext_vector_type(8))) short bf16x8;
typedef __attribute__((ext_vector_type(4))) float f32x4;
typedef __attribute__((ext_vector_type(8))) unsigned short u16x8;

// XOR swizzle: 64-byte rows (32 bf16), 16B chunk permuted by row bits 1..2.
// Breaks the 8-way bank conflict of stride-64B ds_read_b128 columns.
__device__ __forceinline__ int swz(int row, int kb) {
    return row * 64 + ((((kb >> 4) ^ (row >> 1)) & 3) << 4) + (kb & 15);
}

__device__ __forceinline__ unsigned short f2bf(float f) {
    unsigned int u = __float_as_uint(f);
    u += 0x7fffu + ((u >> 16) & 1u);   // round-to-nearest-even
    return (unsigned short)(u >> 16);
}

__global__ void sort_kernel(const int* __restrict__ idx, int* __restrict__ perm,
                            int* __restrict__ off) {
    __shared__ int cnt[NEXP];
    __shared__ int base[NEXP];
    int tid = threadIdx.x;
    if (tid < NEXP) cnt[tid] = 0;
    __syncthreads();
    for (int i = tid; i < TOKENS; i += blockDim.x) atomicAdd(&cnt[idx[i]], 1);
    __syncthreads();
    if (tid == 0) {
        int s = 0;
        for (int e = 0; e < NEXP; ++e) { off[e] = s; base[e] = s; s += cnt[e]; }
        off[NEXP] = s;
    }
    __syncthreads();
    for (int i = tid; i < TOKENS; i += blockDim.x) {
        int e = idx[i];
        int p = atomicAdd(&base[e], 1);
        perm[p] = i;
    }
}

// GEMM1: h[sorted_pos][0..4096) = gelu(x[tok] @ W1[e] + b1[e]), bf16 out.
__launch_bounds__(256, 2)
__global__ void moe_gemm1(const float* __restrict__ x,
                          const float* __restrict__ w1,
                          const float* __restrict__ b1,
                          const int* __restrict__ perm,
                          const int* __restrict__ off,
                          unsigned short* __restrict__ h) {
    const int e  = blockIdx.y >> 6;
    const int mt = blockIdx.y & 63;
    const int segb = off[e];
    const int sege = off[e + 1];
    const int m0g = segb + mt * 128;
    if (m0g >= sege) return;
    const int n0 = blockIdx.x * 128;

    __shared__ __align__(16) unsigned char As[128 * 64];
    __shared__ __align__(16) unsigned char Bs[128 * 64];
    __shared__ int perm_l[128];

    const int tid = threadIdx.x;
    if (tid < 128) {
        int s = m0g + tid;
        perm_l[tid] = (s < sege) ? perm[s] : -1;
    }
    __syncthreads();

    const float* w1e = w1 + (size_t)e * IN_F * HID_F;

    const int wid = tid >> 6, lane = tid & 63;
    const int wm = (wid >> 1) * 64, wn = (wid & 1) * 64;
    const int lr = lane & 15, lkb = (lane >> 4) << 4;

    f32x4 acc[4][4];
#pragma unroll
    for (int i = 0; i < 4; ++i)
#pragma unroll
        for (int j = 0; j < 4; ++j) acc[i][j] = (f32x4){0.f, 0.f, 0.f, 0.f};

    for (int k0 = 0; k0 < IN_F; k0 += 32) {
        __syncthreads();
        // Stage A: 128 rows x 32 k, fp32 -> bf16, gathered by perm.
#pragma unroll
        for (int j = 0; j < 4; ++j) {
            int id = tid + j * 256;
            int row = id >> 3, c4 = id & 7;
            int p = perm_l[row]; if (p < 0) p = perm_l[0];
            float4 v = *(const float4*)(x + (size_t)p * IN_F + k0 + c4 * 4);
            unsigned long long pk =
                (unsigned long long)f2bf(v.x) |
                ((unsigned long long)f2bf(v.y) << 16) |
                ((unsigned long long)f2bf(v.z) << 32) |
                ((unsigned long long)f2bf(v.w) << 48);
            *(unsigned long long*)(As + swz(row, c4 * 8)) = pk;
        }
        // Stage B transposed: Bs[n][k] = W1[k0+k][n0+n], fp32 -> bf16.
#pragma unroll
        for (int j = 0; j < 4; ++j) {
            int id = tid + j * 256;
            int kk = id >> 5, c4 = id & 31;
            float4 v = *(const float4*)(w1e + (size_t)(k0 + kk) * HID_F + n0 + c4 * 4);
            int nr = c4 * 4;
            *(unsigned short*)(Bs + swz(nr + 0, kk * 2)) = f2bf(v.x);
            *(unsigned short*)(Bs + swz(nr + 1, kk * 2)) = f2bf(v.y);
            *(unsigned short*)(Bs + swz(nr + 2, kk * 2)) = f2bf(v.z);
            *(unsigned short*)(Bs + swz(nr + 3, kk * 2)) = f2bf(v.w);
        }
        __syncthreads();

        bf16x8 a[4], b[4];
#pragma unroll
        for (int m = 0; m < 4; ++m)
            a[m] = *(const bf16x8*)(As + swz(wm + m * 16 + lr, lkb));
#pragma unroll
        for (int n = 0; n < 4; ++n)
            b[n] = *(const bf16x8*)(Bs + swz(wn + n * 16 + lr, lkb));
#pragma unroll
        for (int m = 0; m < 4; ++m)
#pragma unroll
            for (int n = 0; n < 4; ++n)
                acc[m][n] = __builtin_amdgcn_mfma_f32_16x16x32_bf16(a[m], b[n], acc[m][n], 0, 0, 0);
    }

    const float* b1e = b1 + (size_t)e * HID_F + n0;
#pragma unroll
    for (int m = 0; m < 4; ++m) {
        int rb = wm + m * 16 + ((lane >> 4) << 2);
#pragma unroll
        for (int r = 0; r < 4; ++r) {
            int row = rb + r;
            if (perm_l[row] < 0) continue;
            size_t hbase = (size_t)(m0g + row) * HID_F + n0;
#pragma unroll
            for (int n = 0; n < 4; ++n) {
                int col = wn + n * 16 + lr;
                float v = acc[m][n][r] + b1e[col];
                float g = 0.5f * v * (1.0f + erff(v * 0.70710678118654752f));
                h[hbase + col] = f2bf(g);
            }
        }
    }
}

// GEMM2: out[tok][0..1024) = h[sorted] @ W2[e] + b2[e], fp32 out (scattered).
__launch_bounds__(256, 2)
__global__ void moe_gemm2(const unsigned short* __restrict__ h,
                          const float* __restrict__ w2,
                          const float* __restrict__ b2,
                          const int* __restrict__ perm,
                          const int* __restrict__ off,
                          float* __restrict__ out) {
    const int e  = blockIdx.y >> 6;
    const int mt = blockIdx.y & 63;
    const int segb = off[e];
    const int sege = off[e + 1];
    const int m0g = segb + mt * 128;
    if (m0g >= sege) return;
    const int n0 = blockIdx.x * 128;

    __shared__ __align__(16) unsigned char As[128 * 64];
    __shared__ __align__(16) unsigned char Bs[128 * 64];
    __shared__ int perm_l[128];

    const int tid = threadIdx.x;
    if (tid < 128) {
        int s = m0g + tid;
        perm_l[tid] = (s < sege) ? perm[s] : -1;
    }
    __syncthreads();

    const float* w2e = w2 + (size_t)e * HID_F * OUT_F;

    const int wid = tid >> 6, lane = tid & 63;
    const int wm = (wid >> 1) * 64, wn = (wid & 1) * 64;
    const int lr = lane & 15, lkb = (lane >> 4) << 4;

    f32x4 acc[4][4];
#pragma unroll
    for (int i = 0; i < 4; ++i)
#pragma unroll
        for (int j = 0; j < 4; ++j) acc[i][j] = (f32x4){0.f, 0.f, 0.f, 0.f};

    for (int k0 = 0; k0 < HID_F; k0 += 32) {
        __syncthreads();
        // Stage A: bf16 h rows (contiguous sorted positions), 16B chunks.
#pragma unroll
        for (int j = 0; j < 2; ++j) {
            int id = tid + j * 256;
            int row = id >> 2, ch = id & 3;
            int hr = m0g + row; if (hr > TOKENS - 1) hr = TOKENS - 1;
            u16x8 v = *(const u16x8*)(h + (size_t)hr * HID_F + k0 + ch * 8);
            *(u16x8*)(As + swz(row, ch * 16)) = v;
        }
        // Stage B transposed: Bs[n][k] = W2[k0+k][n0+n], fp32 -> bf16.
#pragma unroll
        for (int j = 0; j < 4; ++j) {
            int id = tid + j * 256;
            int kk = id >> 5, c4 = id & 31;
            float4 v = *(const float4*)(w2e + (size_t)(k0 + kk) * OUT_F + n0 + c4 * 4);
            int nr = c4 * 4;
            *(unsigned short*)(Bs + swz(nr + 0, kk * 2)) = f2bf(v.x);
            *(unsigned short*)(Bs + swz(nr + 1, kk * 2)) = f2bf(v.y);
            *(unsigned short*)(Bs + swz(nr + 2, kk * 2)) = f2bf(v.z);
            *(unsigned short*)(Bs + swz(nr + 3, kk * 2)) = f2bf(v.w);
        }
        __syncthreads();

        bf16x8 a[4], b[4];
#pragma unroll
        for (int m = 0; m < 4; ++m)
            a[m] = *(const bf16x8*)(As + swz(wm + m * 16 + lr, lkb));
#pragma unroll
        for (int n = 0; n < 4; ++n)
            b[n] = *(const bf16x8*)(Bs + swz(wn + n * 16 + lr, lkb));
#pragma unroll
        for (int m = 0; m < 4; ++m)
#pragma unroll
            for (int n = 0; n < 4; ++n)
                acc[m][n] = __builtin_amdgcn_mfma_f32_16x16x32_bf16(a[m], b[n], acc[m][n], 0, 0, 0);
    }

    const float* b2e = b2 + (size_t)e * OUT_F + n0;
#pragma unroll
    for (int m = 0; m < 4; ++m) {
        int rb = wm + m * 16 + ((lane >> 4) << 2);
#pragma unroll
        for (int r = 0; r < 4; ++r) {
            int row = rb + r;
            int tok = perm_l[row];
            if (tok < 0) continue;
            size_t obase = (size_t)tok * OUT_F + n0;
#pragma unroll
            for (int n = 0; n < 4; ++n) {
                int col = wn + n * 16 + lr;
                out[obase + col] = acc[m][n][r] + b2e[col];
            }
        }
    }
}

extern "C" void kernel_launch(void* const* d_in, const int* in_sizes, int n_in,
                              void* d_out, int out_size, void* d_ws, size_t ws_size,
                              hipStream_t stream) {
    const float* x  = (const float*)d_in[0];
    const int*   idx = (const int*)d_in[1];
    const float* w1 = (const float*)d_in[2];
    const float* w2 = (const float*)d_in[3];
    const float* b1 = (const float*)d_in[4];
    const float* b2 = (const float*)d_in[5];
    float* out = (float*)d_out;

    int* perm = (int*)d_ws;
    int* off  = perm + TOKENS;
    unsigned short* h = (unsigned short*)((char*)d_ws + 65536);

    hipLaunchKernelGGL(sort_kernel, dim3(1), dim3(256), 0, stream, idx, perm, off);
    hipLaunchKernelGGL(moe_gemm1, dim3(32, NEXP * 64), dim3(256), 0, stream,
                       x, w1, b1, perm, off, h);
    hipLaunchKernelGGL(moe_gemm2, dim3(8, NEXP * 64), dim3(256), 0, stream,
                       h, w2, b2, perm, off, out);
}

// Round 2
// 416.456 us; speedup vs baseline: 2.2154x; 2.2154x over previous
//
#include <hip/hip_runtime.h>
#include <hip/hip_bf16.h>
#include <math.h>

#define TOKENS 8192
#define IN_F   1024
#define HID_F  4096
#define OUT_F  1024
#define NEXP   8

typedef __attribute__((ext_vector_type(8))) short bf16x8;
typedef __attribute__((ext_vector_type(4))) float f32x4;
typedef __attribute__((ext_vector_type(8))) unsigned short u16x8;

__device__ __forceinline__ unsigned short f2bf(float f) {
    unsigned int u = __float_as_uint(f);
    u += 0x7fffu + ((u >> 16) & 1u);   // round-to-nearest-even
    return (unsigned short)(u >> 16);
}

__device__ __forceinline__ void gload_lds16(const unsigned short* g, unsigned char* lds) {
    __builtin_amdgcn_global_load_lds(
        (const __attribute__((address_space(1))) void*)g,
        (__attribute__((address_space(3))) void*)lds, 16, 0, 0);
}

// ---------------- sort: wave-aggregated counting sort over 8 experts --------
__global__ void sort_kernel(const int* __restrict__ idx, int* __restrict__ perm,
                            int* __restrict__ off) {
    __shared__ int cnt[NEXP];
    __shared__ int base[NEXP];
    const int tid = threadIdx.x, lane = tid & 63;
    if (tid < NEXP) cnt[tid] = 0;
    __syncthreads();
    for (int i = tid; i < TOKENS; i += 256) {
        int e = idx[i];
#pragma unroll
        for (int ex = 0; ex < NEXP; ++ex) {
            unsigned long long m = __ballot(e == ex);
            if (lane == 0 && m) atomicAdd(&cnt[ex], __popcll(m));
        }
    }
    __syncthreads();
    if (tid == 0) {
        int s = 0;
        for (int e = 0; e < NEXP; ++e) { off[e] = s; base[e] = s; s += cnt[e]; }
        off[NEXP] = s;
    }
    __syncthreads();
    for (int i = tid; i < TOKENS; i += 256) {
        int e = idx[i];
#pragma unroll
        for (int ex = 0; ex < NEXP; ++ex) {
            unsigned long long m = __ballot(e == ex);
            if (e == ex) {
                int lead = (int)__ffsll((long long)m) - 1;
                int pos = 0;
                if (lane == lead) pos = atomicAdd(&base[ex], __popcll(m));
                pos = __shfl(pos, lead);
                pos += __popcll(m & ((1ULL << lane) - 1ULL));
                perm[pos] = i;
            }
        }
    }
}

// ---------------- gather + convert x into sorted bf16 rows ------------------
__global__ void gather_x(const float* __restrict__ x, const int* __restrict__ perm,
                         unsigned short* __restrict__ xg) {
    const int row = blockIdx.x, t = threadIdx.x;
    const int src = perm[row];
    float4 v = *(const float4*)(x + (size_t)src * IN_F + t * 4);
    unsigned long long pk =
        (unsigned long long)f2bf(v.x) |
        ((unsigned long long)f2bf(v.y) << 16) |
        ((unsigned long long)f2bf(v.z) << 32) |
        ((unsigned long long)f2bf(v.w) << 48);
    *(unsigned long long*)(xg + (size_t)row * IN_F + t * 4) = pk;
}

// ---------------- transpose + convert: fp32 [E][R][C] -> bf16 [E][C][R] -----
__global__ void transp(const float* __restrict__ in, unsigned short* __restrict__ out,
                       int R, int C) {
    __shared__ unsigned short T[64][68];   // pad 4 u16: row stride 136B (8B aligned)
    const int e = blockIdx.z;
    const int r0 = blockIdx.y * 64, c0 = blockIdx.x * 64;
    const int tid = threadIdx.x;
    const float* ip = in + ((size_t)e * R + r0) * C + c0;
    const int rr = tid >> 4, cc = tid & 15;
#pragma unroll
    for (int p = 0; p < 4; ++p) {
        int r = p * 16 + rr;
        float4 v = *(const float4*)(ip + (size_t)r * C + cc * 4);
        unsigned long long pk =
            (unsigned long long)f2bf(v.x) |
            ((unsigned long long)f2bf(v.y) << 16) |
            ((unsigned long long)f2bf(v.z) << 32) |
            ((unsigned long long)f2bf(v.w) << 48);
        *(unsigned long long*)&T[r][cc * 4] = pk;
    }
    __syncthreads();
    unsigned short* op = out + ((size_t)e * C + c0) * R + r0;
#pragma unroll
    for (int p = 0; p < 2; ++p) {
        int task = tid + p * 256;
        int c = task >> 3, ch = task & 7;
        u16x8 vv;
#pragma unroll
        for (int i = 0; i < 8; ++i) vv[i] = T[ch * 8 + i][c];
        *(u16x8*)(op + (size_t)c * R + ch * 8) = vv;
    }
}

// ---------------- grouped GEMM, m97 structure -------------------------------
// A [8192][K] bf16 (sorted rows), W [NEXP][ND][K] bf16, bias fp32 [NEXP][ND].
// GELU=true: out = h bf16 [8192][ND] (sorted). GELU=false: out fp32 scattered by perm.
template<int K, int ND, bool GELU>
__launch_bounds__(256, 2)
__global__ void moe_gemm(const unsigned short* __restrict__ A,
                         const unsigned short* __restrict__ W,
                         const float* __restrict__ bias,
                         const int* __restrict__ perm,
                         const int* __restrict__ off,
                         void* __restrict__ outp) {
    const int e  = blockIdx.y >> 6;
    const int mt = blockIdx.y & 63;
    const int segb = off[e], sege = off[e + 1];
    const int m0 = segb + mt * 128;
    if (m0 >= sege) return;
    const int n0 = blockIdx.x * 128;

    __shared__ __align__(16) unsigned char As[16384];   // [128 rows][128B], chunk-swizzled
    __shared__ __align__(16) unsigned char Bs[16384];

    const int tid = threadIdx.x;
    const int wid = tid >> 6, lane = tid & 63;
    const int wm = (wid >> 1) * 64, wn = (wid & 1) * 64;
    const int lr = lane & 15, hk = lane >> 4;

    const unsigned short* We = W + (size_t)e * ND * K + (size_t)n0 * K;

    // staging: per wave-call, 8 rows x 8 chunks of 16B, linear LDS dest.
    // LDS[row][c] holds global chunk c ^ (row&7)  (XOR involution).
    const int srow   = lane >> 3;                 // row within 8-row group
    const int schunk = (lane & 7) ^ srow;         // swizzled source chunk

    f32x4 acc[4][4];
#pragma unroll
    for (int i = 0; i < 4; ++i)
#pragma unroll
        for (int j = 0; j < 4; ++j) acc[i][j] = (f32x4){0.f, 0.f, 0.f, 0.f};

    for (int k0 = 0; k0 < K; k0 += 64) {
        __syncthreads();
#pragma unroll
        for (int j = 0; j < 4; ++j) {
            int rt = (wid * 4 + j) * 8 + srow;
            int ga = m0 + rt; if (ga > TOKENS - 1) ga = TOKENS - 1;
            gload_lds16(A  + (size_t)ga * K + k0 + schunk * 8, As + (wid * 4 + j) * 1024);
            gload_lds16(We + (size_t)rt * K + k0 + schunk * 8, Bs + (wid * 4 + j) * 1024);
        }
        __syncthreads();   // compiler inserts vmcnt(0) drain here
#pragma unroll
        for (int kk = 0; kk < 2; ++kk) {
            bf16x8 a[4], b[4];
#pragma unroll
            for (int m = 0; m < 4; ++m) {
                int row = wm + m * 16 + lr;
                a[m] = *(const bf16x8*)(As + row * 128 + (((kk * 4 + hk) ^ (lr & 7)) * 16));
            }
#pragma unroll
            for (int n = 0; n < 4; ++n) {
                int row = wn + n * 16 + lr;
                b[n] = *(const bf16x8*)(Bs + row * 128 + (((kk * 4 + hk) ^ (lr & 7)) * 16));
            }
#pragma unroll
            for (int m = 0; m < 4; ++m)
#pragma unroll
                for (int n = 0; n < 4; ++n)
                    acc[m][n] = __builtin_amdgcn_mfma_f32_16x16x32_bf16(a[m], b[n], acc[m][n], 0, 0, 0);
        }
    }

    const float* be = bias + (size_t)e * ND + n0;
#pragma unroll
    for (int m = 0; m < 4; ++m) {
#pragma unroll
        for (int r = 0; r < 4; ++r) {
            int row = wm + m * 16 + hk * 4 + r;
            int grow = m0 + row;
            if (grow >= sege) continue;
            if constexpr (GELU) {
                unsigned short* h = (unsigned short*)outp;
                size_t base = (size_t)grow * ND + n0;
#pragma unroll
                for (int n = 0; n < 4; ++n) {
                    int col = wn + n * 16 + lr;
                    float v = acc[m][n][r] + be[col];
                    float g = 0.5f * v * (1.0f + erff(v * 0.70710678118654752f));
                    h[base + col] = f2bf(g);
                }
            } else {
                float* out = (float*)outp;
                int tok = perm[grow];
                size_t base = (size_t)tok * ND + n0;
#pragma unroll
                for (int n = 0; n < 4; ++n) {
                    int col = wn + n * 16 + lr;
                    out[base + col] = acc[m][n][r] + be[col];
                }
            }
        }
    }
}

extern "C" void kernel_launch(void* const* d_in, const int* in_sizes, int n_in,
                              void* d_out, int out_size, void* d_ws, size_t ws_size,
                              hipStream_t stream) {
    const float* x   = (const float*)d_in[0];
    const int*   idx = (const int*)d_in[1];
    const float* w1  = (const float*)d_in[2];
    const float* w2  = (const float*)d_in[3];
    const float* b1  = (const float*)d_in[4];
    const float* b2  = (const float*)d_in[5];
    float* out = (float*)d_out;

    int* perm = (int*)d_ws;
    int* off  = perm + TOKENS;
    unsigned short* xg = (unsigned short*)((char*)d_ws + 65536);
    unsigned short* h  = xg + (size_t)TOKENS * IN_F;
    unsigned short* wt = h + (size_t)TOKENS * HID_F;   // shared W1t/W2t buffer (64MB)

    hipLaunchKernelGGL(sort_kernel, dim3(1), dim3(256), 0, stream, idx, perm, off);
    hipLaunchKernelGGL(gather_x, dim3(TOKENS), dim3(256), 0, stream, x, perm, xg);

    // W1 [E][1024][4096] -> wt [E][4096][1024]
    hipLaunchKernelGGL(transp, dim3(HID_F / 64, IN_F / 64, NEXP), dim3(256), 0, stream,
                       w1, wt, IN_F, HID_F);
    hipLaunchKernelGGL((moe_gemm<IN_F, HID_F, true>), dim3(HID_F / 128, NEXP * 64), dim3(256),
                       0, stream, xg, wt, b1, perm, off, (void*)h);

    // W2 [E][4096][1024] -> wt [E][1024][4096]
    hipLaunchKernelGGL(transp, dim3(OUT_F / 64, HID_F / 64, NEXP), dim3(256), 0, stream,
                       w2, wt, HID_F, OUT_F);
    hipLaunchKernelGGL((moe_gemm<HID_F, OUT_F, false>), dim3(OUT_F / 128, NEXP * 64), dim3(256),
                       0, stream, h, wt, b2, perm, off, (void*)out);
}

// Round 3
// 351.065 us; speedup vs baseline: 2.6281x; 1.1863x over previous
//
#include <hip/hip_runtime.h>
#include <hip/hip_bf16.h>
#include <math.h>

#define TOKENS 8192
#define IN_F   1024
#define HID_F  4096
#define OUT_F  1024
#define NEXP   8
#define TSLOTS 72   // max total M-tiles: TOKENS/128 + NEXP partials

typedef __attribute__((ext_vector_type(8))) short bf16x8;
typedef __attribute__((ext_vector_type(4))) float f32x4;
typedef __attribute__((ext_vector_type(8))) unsigned short u16x8;

__device__ __forceinline__ unsigned short f2bf(float f) {
    unsigned int u = __float_as_uint(f);
    u += 0x7fffu + ((u >> 16) & 1u);   // round-to-nearest-even
    return (unsigned short)(u >> 16);
}

__device__ __forceinline__ void gload_lds16(const unsigned short* g, unsigned char* lds) {
    __builtin_amdgcn_global_load_lds(
        (const __attribute__((address_space(1))) void*)g,
        (__attribute__((address_space(3))) void*)lds, 16, 0, 0);
}

// ---------------- sort + tile-table build -----------------------------------
__global__ void sort_kernel(const int* __restrict__ idx, int* __restrict__ perm,
                            int* __restrict__ off, int* __restrict__ table) {
    __shared__ int cnt[NEXP];
    __shared__ int base[NEXP];
    const int tid = threadIdx.x, lane = tid & 63;
    if (tid < NEXP) cnt[tid] = 0;
    __syncthreads();
    for (int i = tid; i < TOKENS; i += 1024) {
        int e = idx[i];
#pragma unroll
        for (int ex = 0; ex < NEXP; ++ex) {
            unsigned long long m = __ballot(e == ex);
            if (lane == 0 && m) atomicAdd(&cnt[ex], __popcll(m));
        }
    }
    __syncthreads();
    if (tid == 0) {
        int s = 0;
        for (int e = 0; e < NEXP; ++e) { off[e] = s; base[e] = s; s += cnt[e]; }
        off[NEXP] = s;
        int t = 0;
        for (int e = 0; e < NEXP; ++e)
            for (int m0 = off[e]; m0 < off[e + 1]; m0 += 128)
                table[t++] = (e << 13) | m0;
        for (; t < TSLOTS; ++t) table[t] = -1;
    }
    __syncthreads();
    for (int i = tid; i < TOKENS; i += 1024) {
        int e = idx[i];
#pragma unroll
        for (int ex = 0; ex < NEXP; ++ex) {
            unsigned long long m = __ballot(e == ex);
            if (e == ex) {
                int lead = (int)__ffsll((long long)m) - 1;
                int pos = 0;
                if (lane == lead) pos = atomicAdd(&base[ex], __popcll(m));
                pos = __shfl(pos, lead);
                pos += __popcll(m & ((1ULL << lane) - 1ULL));
                perm[pos] = i;
            }
        }
    }
}

// ---------------- gather + convert x into sorted bf16 rows ------------------
__global__ void gather_x(const float* __restrict__ x, const int* __restrict__ perm,
                         unsigned short* __restrict__ xg) {
    const int row = blockIdx.x, t = threadIdx.x;
    const int src = perm[row];
    float4 v = *(const float4*)(x + (size_t)src * IN_F + t * 4);
    unsigned long long pk =
        (unsigned long long)f2bf(v.x) |
        ((unsigned long long)f2bf(v.y) << 16) |
        ((unsigned long long)f2bf(v.z) << 32) |
        ((unsigned long long)f2bf(v.w) << 48);
    *(unsigned long long*)(xg + (size_t)row * IN_F + t * 4) = pk;
}

// ---------------- transpose + convert: fp32 [E][R][C] -> bf16 [E][C][R] -----
// LDS stride 65 u16: both phases 2-way-bank-conflict-free (free on CDNA4).
__global__ void transp(const float* __restrict__ in, unsigned short* __restrict__ out,
                       int R, int C) {
    __shared__ unsigned short T[64 * 65];
    const int e = blockIdx.z;
    const int r0 = blockIdx.y * 64, c0 = blockIdx.x * 64;
    const int tid = threadIdx.x;
    const int rr = tid >> 4, cc = tid & 15;
    const float* ip = in + ((size_t)e * R + r0) * C + c0;
#pragma unroll
    for (int p = 0; p < 4; ++p) {
        int r = p * 16 + rr;
        float4 v = *(const float4*)(ip + (size_t)r * C + cc * 4);
        T[(cc * 4 + 0) * 65 + r] = f2bf(v.x);
        T[(cc * 4 + 1) * 65 + r] = f2bf(v.y);
        T[(cc * 4 + 2) * 65 + r] = f2bf(v.z);
        T[(cc * 4 + 3) * 65 + r] = f2bf(v.w);
    }
    __syncthreads();
    unsigned short* op = out + ((size_t)e * C + c0) * R + r0;
    const int c = tid >> 2, ch = tid & 3;
    u16x8 a, b;
#pragma unroll
    for (int i = 0; i < 8; ++i) a[i] = T[c * 65 + ch * 16 + i];
#pragma unroll
    for (int i = 0; i < 8; ++i) b[i] = T[c * 65 + ch * 16 + 8 + i];
    *(u16x8*)(op + (size_t)c * R + ch * 16) = a;
    *(u16x8*)(op + (size_t)c * R + ch * 16 + 8) = b;
}

// ---------------- grouped GEMM, m97 structure, tile-table driven ------------
// A [8192][K] bf16 (sorted rows), W [NEXP][ND][K] bf16, bias fp32 [NEXP][ND].
// GELU=true: out = h bf16 [8192][ND] (sorted). GELU=false: out fp32 scattered by perm.
template<int K, int ND, bool GELU>
__launch_bounds__(256, 2)
__global__ void moe_gemm(const unsigned short* __restrict__ A,
                         const unsigned short* __restrict__ W,
                         const float* __restrict__ bias,
                         const int* __restrict__ perm,
                         const int* __restrict__ off,
                         const int* __restrict__ table,
                         void* __restrict__ outp) {
    // 1D grid, chunked XCD swizzle: each XCD owns a contiguous logical range;
    // logical order = n-panel outer, expert-tile inner -> W panel L2 reuse.
    const int nwg = (ND / 128) * TSLOTS;
    const int chunk = nwg >> 3;
    const int bid = blockIdx.x;
    const int logical = (bid & 7) * chunk + (bid >> 3);
    const int nt = logical / TSLOTS;
    const int t  = logical - nt * TSLOTS;
    const int te = table[t];
    if (te < 0) return;
    const int e  = te >> 13;
    const int m0 = te & 8191;
    const int sege = off[e + 1];
    const int n0 = nt * 128;

    __shared__ __align__(16) unsigned char As[16384];   // [128 rows][128B], chunk-swizzled
    __shared__ __align__(16) unsigned char Bs[16384];

    const int tid = threadIdx.x;
    const int wid = tid >> 6, lane = tid & 63;
    const int wm = (wid >> 1) * 64, wn = (wid & 1) * 64;
    const int lr = lane & 15, hk = lane >> 4;

    const unsigned short* We = W + (size_t)e * ND * K + (size_t)n0 * K;

    // staging: per wave-call, 8 rows x 8 chunks of 16B, linear LDS dest.
    // LDS[row][c] holds global chunk c ^ (row&7)  (XOR involution).
    const int srow   = lane >> 3;
    const int schunk = (lane & 7) ^ srow;

    f32x4 acc[4][4];
#pragma unroll
    for (int i = 0; i < 4; ++i)
#pragma unroll
        for (int j = 0; j < 4; ++j) acc[i][j] = (f32x4){0.f, 0.f, 0.f, 0.f};

    for (int k0 = 0; k0 < K; k0 += 64) {
        __syncthreads();
#pragma unroll
        for (int j = 0; j < 4; ++j) {
            int rt = (wid * 4 + j) * 8 + srow;
            int ga = m0 + rt; if (ga > TOKENS - 1) ga = TOKENS - 1;
            gload_lds16(A  + (size_t)ga * K + k0 + schunk * 8, As + (wid * 4 + j) * 1024);
            gload_lds16(We + (size_t)rt * K + k0 + schunk * 8, Bs + (wid * 4 + j) * 1024);
        }
        __syncthreads();
#pragma unroll
        for (int kk = 0; kk < 2; ++kk) {
            bf16x8 a[4], b[4];
#pragma unroll
            for (int m = 0; m < 4; ++m) {
                int row = wm + m * 16 + lr;
                a[m] = *(const bf16x8*)(As + row * 128 + (((kk * 4 + hk) ^ (lr & 7)) * 16));
            }
#pragma unroll
            for (int n = 0; n < 4; ++n) {
                int row = wn + n * 16 + lr;
                b[n] = *(const bf16x8*)(Bs + row * 128 + (((kk * 4 + hk) ^ (lr & 7)) * 16));
            }
#pragma unroll
            for (int m = 0; m < 4; ++m)
#pragma unroll
                for (int n = 0; n < 4; ++n)
                    acc[m][n] = __builtin_amdgcn_mfma_f32_16x16x32_bf16(a[m], b[n], acc[m][n], 0, 0, 0);
        }
    }

    const float* be = bias + (size_t)e * ND + n0;
#pragma unroll
    for (int m = 0; m < 4; ++m) {
#pragma unroll
        for (int r = 0; r < 4; ++r) {
            int row = wm + m * 16 + hk * 4 + r;
            int grow = m0 + row;
            if (grow >= sege) continue;
            if constexpr (GELU) {
                unsigned short* h = (unsigned short*)outp;
                size_t base = (size_t)grow * ND + n0;
#pragma unroll
                for (int n = 0; n < 4; ++n) {
                    int col = wn + n * 16 + lr;
                    float v = acc[m][n][r] + be[col];
                    // gelu(v) = v * sigmoid(2 * 0.79788456*(v + 0.044715 v^3))
                    float u = v * (0.7978845608f + 0.0356774081f * v * v);
                    float g = v / (1.0f + __expf(-2.0f * u));
                    h[base + col] = f2bf(g);
                }
            } else {
                float* out = (float*)outp;
                int tok = perm[grow];
                size_t base = (size_t)tok * ND + n0;
#pragma unroll
                for (int n = 0; n < 4; ++n) {
                    int col = wn + n * 16 + lr;
                    out[base + col] = acc[m][n][r] + be[col];
                }
            }
        }
    }
}

extern "C" void kernel_launch(void* const* d_in, const int* in_sizes, int n_in,
                              void* d_out, int out_size, void* d_ws, size_t ws_size,
                              hipStream_t stream) {
    const float* x   = (const float*)d_in[0];
    const int*   idx = (const int*)d_in[1];
    const float* w1  = (const float*)d_in[2];
    const float* w2  = (const float*)d_in[3];
    const float* b1  = (const float*)d_in[4];
    const float* b2  = (const float*)d_in[5];
    float* out = (float*)d_out;

    int* perm  = (int*)d_ws;
    int* off   = perm + TOKENS;
    int* table = off + 16;
    unsigned short* xg = (unsigned short*)((char*)d_ws + 65536);
    unsigned short* h  = xg + (size_t)TOKENS * IN_F;
    unsigned short* wt = h + (size_t)TOKENS * HID_F;   // shared W1t/W2t buffer (64MB)

    hipLaunchKernelGGL(sort_kernel, dim3(1), dim3(1024), 0, stream, idx, perm, off, table);
    hipLaunchKernelGGL(gather_x, dim3(TOKENS), dim3(256), 0, stream, x, perm, xg);

    // W1 [E][1024][4096] -> wt [E][4096][1024]
    hipLaunchKernelGGL(transp, dim3(HID_F / 64, IN_F / 64, NEXP), dim3(256), 0, stream,
                       w1, wt, IN_F, HID_F);
    hipLaunchKernelGGL((moe_gemm<IN_F, HID_F, true>), dim3((HID_F / 128) * TSLOTS), dim3(256),
                       0, stream, xg, wt, b1, perm, off, table, (void*)h);

    // W2 [E][4096][1024] -> wt [E][1024][4096]
    hipLaunchKernelGGL(transp, dim3(OUT_F / 64, HID_F / 64, NEXP), dim3(256), 0, stream,
                       w2, wt, HID_F, OUT_F);
    hipLaunchKernelGGL((moe_gemm<HID_F, OUT_F, false>), dim3((OUT_F / 128) * TSLOTS), dim3(256),
                       0, stream, h, wt, b2, perm, off, table, (void*)out);
}